// Round 2
// baseline (428.954 us; speedup 1.0000x reference)
//
#include <hip/hip_runtime.h>

#define HW_N 65536
#define CC 192
#define NCHUNKS 128

typedef __attribute__((ext_vector_type(8))) short short8v;
typedef __attribute__((ext_vector_type(4))) short short4v;
typedef __attribute__((ext_vector_type(4))) float f32x4;
typedef __attribute__((ext_vector_type(4))) int int4v;

__device__ __forceinline__ float bf2f(unsigned short u) {
  union { unsigned int i; float f; } v; v.i = ((unsigned int)u) << 16; return v.f;
}
__device__ __forceinline__ unsigned short f2bf(float f) {
  union { float f; unsigned int i; } v; v.f = f;
  unsigned int r = v.i + 0x7fffu + ((v.i >> 16) & 1u);
  return (unsigned short)(r >> 16);
}

// ---------------- transpose [b][192][65536] -> [b][65536][192], out bf16 ----------------
// INF32: input is float32; else input is bf16 (ushort)
template <int INF32>
__global__ __launch_bounds__(256) void transpose_cn(
    const void* __restrict__ in_, unsigned short* __restrict__ out) {
  __shared__ unsigned short tile[64][72];
  const int n0 = blockIdx.x * 64;
  const int c0 = blockIdx.y * 64;
  const int b = blockIdx.z;
  const size_t ob = (size_t)b * HW_N * CC;
  const int t = threadIdx.x;
#pragma unroll
  for (int i = 0; i < 4; ++i) {
    const int idx = t + i * 256;
    const int c = idx >> 4, nc = (idx & 15) * 4;
    unsigned short r[4];
    if (INF32) {
      const float* in = (const float*)in_ + (size_t)b * CC * HW_N;
      f32x4 v = *(const f32x4*)(in + (size_t)(c0 + c) * HW_N + n0 + nc);
#pragma unroll
      for (int j = 0; j < 4; ++j) r[j] = f2bf(v[j]);
    } else {
      const unsigned short* in = (const unsigned short*)in_ + (size_t)b * CC * HW_N;
      short4v v = *(const short4v*)(in + (size_t)(c0 + c) * HW_N + n0 + nc);
#pragma unroll
      for (int j = 0; j < 4; ++j) r[j] = (unsigned short)v[j];
    }
    *(short4v*)&tile[c][nc] = *(short4v*)r;
  }
  __syncthreads();
  const int n = t & 63;
  const int cc2 = (t >> 6) * 16;
  union { short8v v; unsigned short u[8]; } o0, o1;
#pragma unroll
  for (int j = 0; j < 8; ++j) o0.u[j] = tile[cc2 + j][n];
#pragma unroll
  for (int j = 0; j < 8; ++j) o1.u[j] = tile[cc2 + 8 + j][n];
  unsigned short* orow = out + ob + (size_t)(n0 + n) * CC + c0 + cc2;
  *(short8v*)orow = o0.v;
  *(short8v*)(orow + 8) = o1.v;
}

// ---------------- conv1x1 GEMM: out[b][m][n] = W[m][:] . XT[b][n][:] + bias ----------------
// WF32: W is f32 (converted per-fragment); else bf16. OUTF32: write f32; else bf16.
template <int WF32, int OUTF32>
__global__ __launch_bounds__(256) void conv1x1_gemm(
    const unsigned short* __restrict__ XT,   // [B][N][192] bf16
    const void* __restrict__ W_,             // [Mtot][192]
    const float* __restrict__ bias,          // [Mtot] f32
    void* __restrict__ out_,                 // [B][Mtot][N]
    int Mtot, int perBatchW) {
  __shared__ unsigned short Bt[64][200];  // [n][k], +8 pad
  const int n0 = blockIdx.x * 64;
  const int m0 = blockIdx.y * 192;
  const int b = blockIdx.z;
  const int t = threadIdx.x;
  const int lane = t & 63, wv = t >> 6;
  const int l15 = lane & 15, lg = lane >> 4;

  const unsigned short* src = XT + ((size_t)b * HW_N + n0) * CC;
#pragma unroll
  for (int i = 0; i < 6; ++i) {
    const int idx = t + i * 256;
    const int r = idx / 24, ck = idx % 24;
    *(int4v*)&Bt[r][ck * 8] = *(const int4v*)(src + r * CC + ck * 8);
  }
  __syncthreads();

  const size_t wb_off = perBatchW ? (size_t)b * Mtot * CC : 0;
  const int mrow = m0 + wv * 48;
  f32x4 acc[3][4] = {};
#pragma unroll
  for (int ks = 0; ks < 6; ++ks) {
    const int k0 = ks * 32 + lg * 8;
    short8v af[3], bfr[4];
#pragma unroll
    for (int fr = 0; fr < 3; ++fr) {
      if (WF32) {
        const float* p = (const float*)W_ + wb_off + (size_t)(mrow + fr * 16 + l15) * CC + k0;
        unsigned short tmp[8];
#pragma unroll
        for (int j = 0; j < 8; ++j) tmp[j] = f2bf(p[j]);
        af[fr] = *(short8v*)tmp;
      } else {
        const unsigned short* p = (const unsigned short*)W_ + wb_off + (size_t)(mrow + fr * 16 + l15) * CC + k0;
        af[fr] = *(const short8v*)p;
      }
    }
#pragma unroll
    for (int fc = 0; fc < 4; ++fc)
      bfr[fc] = *(const short8v*)&Bt[fc * 16 + l15][k0];
#pragma unroll
    for (int fr = 0; fr < 3; ++fr)
#pragma unroll
      for (int fc = 0; fc < 4; ++fc)
        acc[fr][fc] = __builtin_amdgcn_mfma_f32_16x16x32_bf16(af[fr], bfr[fc], acc[fr][fc], 0, 0, 0);
  }

  const size_t obase = (size_t)b * Mtot * HW_N;
#pragma unroll
  for (int fr = 0; fr < 3; ++fr) {
    const int rbase = mrow + fr * 16 + lg * 4;
#pragma unroll
    for (int r = 0; r < 4; ++r) {
      const float bb = bias[rbase + r];
#pragma unroll
      for (int fc = 0; fc < 4; ++fc) {
        const size_t oi = obase + (size_t)(rbase + r) * HW_N + n0 + fc * 16 + l15;
        if (OUTF32) ((float*)out_)[oi] = acc[fr][fc][r] + bb;
        else ((unsigned short*)out_)[oi] = f2bf(acc[fr][fc][r] + bb);
      }
    }
  }
}

// ---------------- depthwise 3x3, pad=1 (bf16 in/out, f32 weights) ----------------
__global__ __launch_bounds__(256) void dwconv3x3(
    const unsigned short* __restrict__ in, const float* __restrict__ w,
    const float* __restrict__ bias, unsigned short* __restrict__ out0,
    unsigned short* __restrict__ out1, int C, int csplit) {
  const int t = threadIdx.x;
  const int wc = (t & 31) * 8;
  const int h = blockIdx.x * 8 + (t >> 5);
  const int c = blockIdx.y, b = blockIdx.z;
  const size_t base = ((size_t)b * C + c) * (size_t)HW_N;
  float wv9[9];
#pragma unroll
  for (int i = 0; i < 9; ++i) wv9[i] = w[c * 9 + i];
  const float bv = bias[c];
  float f[3][10];
#pragma unroll
  for (int ky = 0; ky < 3; ++ky) {
    const int hh = h + ky - 1;
    if (hh < 0 || hh > 255) {
#pragma unroll
      for (int j = 0; j < 10; ++j) f[ky][j] = 0.f;
    } else {
      const unsigned short* row = in + base + hh * 256;
      short8v v = *(const short8v*)(row + wc);
      f[ky][0] = (wc > 0) ? bf2f(row[wc - 1]) : 0.f;
#pragma unroll
      for (int j = 0; j < 8; ++j) f[ky][1 + j] = bf2f((unsigned short)v[j]);
      f[ky][9] = (wc < 248) ? bf2f(row[wc + 8]) : 0.f;
    }
  }
  union { short8v v; unsigned short u[8]; } o;
#pragma unroll
  for (int j = 0; j < 8; ++j) {
    float acc = bv;
#pragma unroll
    for (int ky = 0; ky < 3; ++ky)
#pragma unroll
      for (int kx = 0; kx < 3; ++kx)
        acc += wv9[ky * 3 + kx] * f[ky][j + kx];
    o.u[j] = f2bf(acc);
  }
  unsigned short* op;
  size_t obase;
  if (c < csplit) { op = out0; obase = ((size_t)b * csplit + c) * (size_t)HW_N; }
  else { op = out1; obase = ((size_t)b * (C - csplit) + (c - csplit)) * (size_t)HW_N; }
  *(short8v*)(op + obase + h * 256 + wc) = o.v;
}

// ---------------- Gram partials: G[c][d] = sum_n Q[c,n]K[d,n]; + sumsq ----------------
__global__ __launch_bounds__(64) void gram_kernel(
    const unsigned short* __restrict__ Q, const unsigned short* __restrict__ K,
    float* __restrict__ Gp, float* __restrict__ nqp, float* __restrict__ nkp) {
  const int lane = threadIdx.x;
  const int l15 = lane & 15, lg = lane >> 4;
  const int chunk = blockIdx.x, h = blockIdx.y, b = blockIdx.z;
  const int bh = b * 6 + h;
  const size_t base = ((size_t)b * CC + h * 32) * (size_t)HW_N;
  f32x4 acc[2][2] = {};
  float sq[2] = {0.f, 0.f}, sk[2] = {0.f, 0.f};
  const int nst = chunk * 512 + lg * 8;
  for (int ks = 0; ks < 16; ++ks) {
    const int n = nst + ks * 32;
    short8v qa[2], kb[2];
#pragma unroll
    for (int fr = 0; fr < 2; ++fr) {
      qa[fr] = *(const short8v*)(Q + base + (size_t)(fr * 16 + l15) * HW_N + n);
      kb[fr] = *(const short8v*)(K + base + (size_t)(fr * 16 + l15) * HW_N + n);
    }
#pragma unroll
    for (int fr = 0; fr < 2; ++fr)
#pragma unroll
      for (int j = 0; j < 8; ++j) {
        float a = bf2f((unsigned short)qa[fr][j]); sq[fr] += a * a;
        float c2 = bf2f((unsigned short)kb[fr][j]); sk[fr] += c2 * c2;
      }
#pragma unroll
    for (int fr = 0; fr < 2; ++fr)
#pragma unroll
      for (int fc = 0; fc < 2; ++fc)
        acc[fr][fc] = __builtin_amdgcn_mfma_f32_16x16x32_bf16(qa[fr], kb[fc], acc[fr][fc], 0, 0, 0);
  }
  float* Gb = Gp + (size_t)(chunk * 12 + bh) * 1024;
#pragma unroll
  for (int fr = 0; fr < 2; ++fr)
#pragma unroll
    for (int fc = 0; fc < 2; ++fc)
#pragma unroll
      for (int r = 0; r < 4; ++r)
        Gb[(fr * 16 + lg * 4 + r) * 32 + fc * 16 + l15] = acc[fr][fc][r];
#pragma unroll
  for (int fr = 0; fr < 2; ++fr) {
    float v = sq[fr]; v += __shfl_down(v, 32); v += __shfl_down(v, 16);
    float u = sk[fr]; u += __shfl_down(u, 32); u += __shfl_down(u, 16);
    if (lane < 16) {
      nqp[(size_t)(chunk * 12 + bh) * 32 + fr * 16 + lane] = v;
      nkp[(size_t)(chunk * 12 + bh) * 32 + fr * 16 + lane] = u;
    }
  }
}

// ---------------- reduce partials ----------------
__global__ __launch_bounds__(256) void reduce_gram(
    const float* __restrict__ Gp, const float* __restrict__ nqp, const float* __restrict__ nkp,
    float* __restrict__ G, float* __restrict__ nq, float* __restrict__ nk) {
  const int i = blockIdx.x * 256 + threadIdx.x;
  if (i < 12 * 1024) {
    float s = 0.f;
    for (int ch = 0; ch < NCHUNKS; ++ch) s += Gp[(size_t)ch * 12288 + i];
    G[i] = s;
  } else if (i < 12 * 1024 + 384) {
    const int j = i - 12 * 1024;
    float s = 0.f;
    for (int ch = 0; ch < NCHUNKS; ++ch) s += nqp[(size_t)ch * 384 + j];
    nq[j] = s;
  } else if (i < 12 * 1024 + 768) {
    const int j = i - 12 * 1024 - 384;
    float s = 0.f;
    for (int ch = 0; ch < NCHUNKS; ++ch) s += nkp[(size_t)ch * 384 + j];
    nk[j] = s;
  }
}

// ---------------- softmax + fold proj: M[b] = proj_w @ blockdiag(attn) ----------------
__global__ __launch_bounds__(256) void attn_proj(
    const float* __restrict__ G, const float* __restrict__ nq, const float* __restrict__ nk,
    const float* __restrict__ temp, const float* __restrict__ proj_w,
    unsigned short* __restrict__ Mout) {
  const int h = blockIdx.x, b = blockIdx.y;
  const int bh = b * 6 + h;
  const int t = threadIdx.x;
  __shared__ float sc[32][33];
  __shared__ float nrmq[32], nrmk[32];
  if (t < 32) nrmq[t] = fmaxf(sqrtf(nq[bh * 32 + t]), 1e-12f);
  else if (t < 64) nrmk[t - 32] = fmaxf(sqrtf(nk[bh * 32 + t - 32]), 1e-12f);
  __syncthreads();
  const float tpr = temp[h];
  for (int i = t; i < 1024; i += 256) {
    const int c = i >> 5, d = i & 31;
    sc[c][d] = G[bh * 1024 + i] * tpr / (nrmq[c] * nrmk[d]);
  }
  __syncthreads();
  if (t < 32) {
    float mx = -1e30f;
    for (int d = 0; d < 32; ++d) mx = fmaxf(mx, sc[t][d]);
    float sum = 0.f;
    for (int d = 0; d < 32; ++d) { float e = __expf(sc[t][d] - mx); sc[t][d] = e; sum += e; }
    const float inv = 1.f / sum;
    for (int d = 0; d < 32; ++d) sc[t][d] *= inv;
  }
  __syncthreads();
  for (int i = t; i < 6144; i += 256) {
    const int co = i >> 5, d = i & 31;
    float acc = 0.f;
    for (int c = 0; c < 32; ++c) acc += proj_w[co * CC + h * 32 + c] * sc[c][d];
    Mout[((size_t)b * CC + co) * CC + h * 32 + d] = f2bf(acc);
  }
}

extern "C" void kernel_launch(void* const* d_in, const int* in_sizes, int n_in,
                              void* d_out, int out_size, void* d_ws, size_t ws_size,
                              hipStream_t stream) {
  const float* fg = (const float*)d_in[0];
  const float* fo = (const float*)d_in[1];
  const float* q_w = (const float*)d_in[2];
  const float* q_b = (const float*)d_in[3];
  const float* kv_w = (const float*)d_in[4];
  const float* kv_b = (const float*)d_in[5];
  const float* q_dw_w = (const float*)d_in[6];
  const float* q_dw_b = (const float*)d_in[7];
  const float* kv_dw_w = (const float*)d_in[8];
  const float* kv_dw_b = (const float*)d_in[9];
  const float* proj_w = (const float*)d_in[10];
  const float* proj_b = (const float*)d_in[11];
  const float* temp = (const float*)d_in[12];

  char* ws = (char*)d_ws;
  // bf16 plane (192ch) = 2*192*65536*2 = 50331648 bytes
  unsigned short* FGT = (unsigned short*)(ws + 0);           // [b][n][192] bf16
  unsigned short* FOT = (unsigned short*)(ws + 50331648);
  unsigned short* QC  = (unsigned short*)(ws + 100663296);   // [b][192][n] bf16
  unsigned short* KVC = (unsigned short*)(ws + 150994944);   // [b][384][n] bf16 (100663296 B)
  // reuse after consumption:
  unsigned short* Qb = FGT;                                   // dw(QC) NCHW
  unsigned short* Kb = FOT;                                   // K half NCHW
  unsigned short* Vb = QC;                                    // V half NCHW
  unsigned short* VT = KVC;                                   // V transposed [b][n][192] (first 50MB of KVC)
  float* Gp  = (float*)(ws + 201326592);                      // [128][12][1024] f32 (6291456 B)
  float* nqp = (float*)(ws + 207618048);                      // [128][12][32]
  float* nkp = (float*)(ws + 207814656);
  float* G   = (float*)(ws + 208011264);                      // [12][1024]
  float* nqv = (float*)(ws + 208060416);
  float* nkv = (float*)(ws + 208061952);
  unsigned short* Mw = (unsigned short*)(ws + 208063488);     // [2][192][192] bf16

  dim3 blk(256);
  transpose_cn<1><<<dim3(1024, 3, 2), blk, 0, stream>>>((const void*)fg, FGT);
  transpose_cn<1><<<dim3(1024, 3, 2), blk, 0, stream>>>((const void*)fo, FOT);
  conv1x1_gemm<1, 0><<<dim3(1024, 1, 2), blk, 0, stream>>>(FGT, (const void*)q_w, q_b, (void*)QC, 192, 0);
  conv1x1_gemm<1, 0><<<dim3(1024, 2, 2), blk, 0, stream>>>(FOT, (const void*)kv_w, kv_b, (void*)KVC, 384, 0);
  dwconv3x3<<<dim3(32, 192, 2), blk, 0, stream>>>(QC, q_dw_w, q_dw_b, Qb, nullptr, 192, 192);
  dwconv3x3<<<dim3(32, 384, 2), blk, 0, stream>>>(KVC, kv_dw_w, kv_dw_b, Kb, Vb, 384, 192);
  transpose_cn<0><<<dim3(1024, 3, 2), blk, 0, stream>>>((const void*)Vb, VT);
  gram_kernel<<<dim3(NCHUNKS, 6, 2), dim3(64), 0, stream>>>(Qb, Kb, Gp, nqp, nkp);
  reduce_gram<<<dim3(51), blk, 0, stream>>>(Gp, nqp, nkp, G, nqv, nkv);
  attn_proj<<<dim3(6, 2), blk, 0, stream>>>(G, nqv, nkv, temp, proj_w, Mw);
  conv1x1_gemm<0, 1><<<dim3(1024, 1, 2), blk, 0, stream>>>(VT, (const void*)Mw, proj_b, d_out, 192, 1);
}

// Round 3
// 311.285 us; speedup vs baseline: 1.3780x; 1.3780x over previous
//
#include <hip/hip_runtime.h>

#define HW_N 65536
#define CC 192
#define NCHUNKS 128

typedef __attribute__((ext_vector_type(8))) short short8v;
typedef __attribute__((ext_vector_type(4))) float f32x4;
typedef __attribute__((ext_vector_type(4))) int int4v;

__device__ __forceinline__ float bf2f(unsigned short u) {
  union { unsigned int i; float f; } v; v.i = ((unsigned int)u) << 16; return v.f;
}
__device__ __forceinline__ unsigned short f2bf(float f) {
  union { float f; unsigned int i; } v; v.f = f;
  unsigned int r = v.i + 0x7fffu + ((v.i >> 16) & 1u);
  return (unsigned short)(r >> 16);
}

// ---------------- weight preconversion f32 -> bf16 ----------------
__global__ __launch_bounds__(256) void cvt_w(
    const float* __restrict__ qw, const float* __restrict__ kvw,
    unsigned short* __restrict__ Wq, unsigned short* __restrict__ Wkv) {
  const int i = (blockIdx.x * 256 + threadIdx.x) * 8;
  const float* src; unsigned short* dst; int off;
  if (i < 36864) { src = qw; dst = Wq; off = i; }
  else { src = kvw; dst = Wkv; off = i - 36864; }
  unsigned short tmp[8];
#pragma unroll
  for (int j = 0; j < 8; ++j) tmp[j] = f2bf(src[off + j]);
  *(short8v*)(dst + off) = *(short8v*)tmp;
}

// ---------------- conv1x1 GEMM from NCHW input (transpose folded into LDS staging) ----
// out[b][m][n] = sum_k W[m][k] * X[b][k][n] + bias[m]
// X: [B][192][65536] (f32 if INF32 else bf16), W bf16 [Mtot][192]
// block: 512 threads = 8 waves; tile 192 rows x 128 cols; wave = 48r x 64c
// grid.x: msplit==1 -> nt = d (512 blocks); msplit==2 -> swizzled so that the two
// m-tiles of one n-tile are 8 dispatches apart (same XCD -> L2 hit on shared X-tile)
template <int INF32, int OUTF32, int PERB>
__global__ __launch_bounds__(512) void conv_gemm(
    const void* __restrict__ X_, const unsigned short* __restrict__ W,
    const float* __restrict__ bias, void* __restrict__ out_,
    int Mtot, int msplit) {
  __shared__ unsigned short Bt[2][128][40];
  const int d = blockIdx.x;
  int mt, nt;
  if (msplit == 2) { mt = (d >> 3) & 1; nt = (d & 7) | ((d >> 4) << 3); }
  else { mt = 0; nt = d; }
  const int m0 = mt * 192, n0 = nt * 128;
  const int b = blockIdx.z;
  const int t = threadIdx.x;
  const int lane = t & 63, wv = t >> 6;
  const int l15 = lane & 15, lg = lane >> 4;
  const int mrow = m0 + (wv & 3) * 48;      // compute role: rows
  const int nw = (wv >> 2) * 64;            // compute role: col half
  const int n_s = lane + 64 * (wv & 1);     // staging role: n (stride-1 per lane)
  const int kq = wv >> 1;                   // staging role: k-octet 0..3
  const size_t xbase = (size_t)b * CC * (size_t)HW_N + n0 + n_s;
  const unsigned short* Wb = W + (PERB ? (size_t)b * Mtot * CC : 0);

  float stg[8];
  // stage chunk 0
#pragma unroll
  for (int j = 0; j < 8; ++j) {
    const size_t xi = xbase + (size_t)(kq * 8 + j) * HW_N;
    stg[j] = INF32 ? ((const float*)X_)[xi] : bf2f(((const unsigned short*)X_)[xi]);
  }
  {
    unsigned short tmp[8];
#pragma unroll
    for (int j = 0; j < 8; ++j) tmp[j] = f2bf(stg[j]);
    *(short8v*)&Bt[0][n_s][kq * 8] = *(short8v*)tmp;
  }
  __syncthreads();

  f32x4 acc[3][4] = {};
  for (int kc = 0; kc < 6; ++kc) {
    const int buf = kc & 1;
    if (kc < 5) {  // T14: issue next chunk's global loads before MFMA phase
#pragma unroll
      for (int j = 0; j < 8; ++j) {
        const size_t xi = xbase + (size_t)((kc + 1) * 32 + kq * 8 + j) * HW_N;
        stg[j] = INF32 ? ((const float*)X_)[xi] : bf2f(((const unsigned short*)X_)[xi]);
      }
    }
    short8v af[3], bfr[4];
    const int k0 = kc * 32 + lg * 8;
#pragma unroll
    for (int fr = 0; fr < 3; ++fr)
      af[fr] = *(const short8v*)(Wb + (size_t)(mrow + fr * 16 + l15) * CC + k0);
#pragma unroll
    for (int fc = 0; fc < 4; ++fc)
      bfr[fc] = *(const short8v*)&Bt[buf][nw + fc * 16 + l15][lg * 8];
#pragma unroll
    for (int fr = 0; fr < 3; ++fr)
#pragma unroll
      for (int fc = 0; fc < 4; ++fc)
        acc[fr][fc] = __builtin_amdgcn_mfma_f32_16x16x32_bf16(af[fr], bfr[fc], acc[fr][fc], 0, 0, 0);
    if (kc < 5) {
      unsigned short tmp[8];
#pragma unroll
      for (int j = 0; j < 8; ++j) tmp[j] = f2bf(stg[j]);
      *(short8v*)&Bt[buf ^ 1][n_s][kq * 8] = *(short8v*)tmp;
    }
    __syncthreads();
  }

  const size_t obase = (size_t)b * Mtot * (size_t)HW_N;
#pragma unroll
  for (int fr = 0; fr < 3; ++fr) {
    const int rbase = mrow + fr * 16 + lg * 4;
#pragma unroll
    for (int r = 0; r < 4; ++r) {
      const float bb = bias[rbase + r];
#pragma unroll
      for (int fc = 0; fc < 4; ++fc) {
        const size_t oi = obase + (size_t)(rbase + r) * HW_N + n0 + nw + fc * 16 + l15;
        if (OUTF32) ((float*)out_)[oi] = acc[fr][fc][r] + bb;
        else ((unsigned short*)out_)[oi] = f2bf(acc[fr][fc][r] + bb);
      }
    }
  }
}

// ---------------- depthwise 3x3, pad=1 (bf16 in/out, f32 weights) ----------------
// in channel index = coff + blockIdx.y within a [b][Cstride][N] tensor; out is [b][192][N]
__global__ __launch_bounds__(256) void dwconv3x3(
    const unsigned short* __restrict__ in, const float* __restrict__ w,
    const float* __restrict__ bias, unsigned short* __restrict__ out,
    int Cstride, int coff) {
  const int t = threadIdx.x;
  const int wc = (t & 31) * 8;
  const int h = blockIdx.x * 8 + (t >> 5);
  const int c = blockIdx.y, b = blockIdx.z;
  const size_t ibase = ((size_t)b * Cstride + coff + c) * (size_t)HW_N;
  const size_t obase = ((size_t)b * CC + c) * (size_t)HW_N;
  float wv9[9];
#pragma unroll
  for (int i = 0; i < 9; ++i) wv9[i] = w[(coff + c) * 9 + i];
  const float bv = bias[coff + c];
  float f[3][10];
#pragma unroll
  for (int ky = 0; ky < 3; ++ky) {
    const int hh = h + ky - 1;
    if (hh < 0 || hh > 255) {
#pragma unroll
      for (int j = 0; j < 10; ++j) f[ky][j] = 0.f;
    } else {
      const unsigned short* row = in + ibase + hh * 256;
      short8v v = *(const short8v*)(row + wc);
      f[ky][0] = (wc > 0) ? bf2f(row[wc - 1]) : 0.f;
#pragma unroll
      for (int j = 0; j < 8; ++j) f[ky][1 + j] = bf2f((unsigned short)v[j]);
      f[ky][9] = (wc < 248) ? bf2f(row[wc + 8]) : 0.f;
    }
  }
  union { short8v v; unsigned short u[8]; } o;
#pragma unroll
  for (int j = 0; j < 8; ++j) {
    float acc = bv;
#pragma unroll
    for (int ky = 0; ky < 3; ++ky)
#pragma unroll
      for (int kx = 0; kx < 3; ++kx)
        acc += wv9[ky * 3 + kx] * f[ky][j + kx];
    o.u[j] = f2bf(acc);
  }
  *(short8v*)(out + obase + h * 256 + wc) = o.v;
}

// ---------------- Gram partials: G[c][d] = sum_n Q[c,n]K[d,n]; + sumsq ----------------
__global__ __launch_bounds__(64) void gram_kernel(
    const unsigned short* __restrict__ Q, const unsigned short* __restrict__ K,
    float* __restrict__ Gp, float* __restrict__ nqp, float* __restrict__ nkp) {
  const int lane = threadIdx.x;
  const int l15 = lane & 15, lg = lane >> 4;
  const int chunk = blockIdx.x, h = blockIdx.y, b = blockIdx.z;
  const int bh = b * 6 + h;
  const size_t base = ((size_t)b * CC + h * 32) * (size_t)HW_N;
  f32x4 acc[2][2] = {};
  float sq[2] = {0.f, 0.f}, sk[2] = {0.f, 0.f};
  const int nst = chunk * 512 + lg * 8;
  for (int ks = 0; ks < 16; ++ks) {
    const int n = nst + ks * 32;
    short8v qa[2], kb[2];
#pragma unroll
    for (int fr = 0; fr < 2; ++fr) {
      qa[fr] = *(const short8v*)(Q + base + (size_t)(fr * 16 + l15) * HW_N + n);
      kb[fr] = *(const short8v*)(K + base + (size_t)(fr * 16 + l15) * HW_N + n);
    }
#pragma unroll
    for (int fr = 0; fr < 2; ++fr)
#pragma unroll
      for (int j = 0; j < 8; ++j) {
        float a = bf2f((unsigned short)qa[fr][j]); sq[fr] += a * a;
        float c2 = bf2f((unsigned short)kb[fr][j]); sk[fr] += c2 * c2;
      }
#pragma unroll
    for (int fr = 0; fr < 2; ++fr)
#pragma unroll
      for (int fc = 0; fc < 2; ++fc)
        acc[fr][fc] = __builtin_amdgcn_mfma_f32_16x16x32_bf16(qa[fr], kb[fc], acc[fr][fc], 0, 0, 0);
  }
  float* Gb = Gp + (size_t)(chunk * 12 + bh) * 1024;
#pragma unroll
  for (int fr = 0; fr < 2; ++fr)
#pragma unroll
    for (int fc = 0; fc < 2; ++fc)
#pragma unroll
      for (int r = 0; r < 4; ++r)
        Gb[(fr * 16 + lg * 4 + r) * 32 + fc * 16 + l15] = acc[fr][fc][r];
#pragma unroll
  for (int fr = 0; fr < 2; ++fr) {
    float v = sq[fr]; v += __shfl_down(v, 32); v += __shfl_down(v, 16);
    float u = sk[fr]; u += __shfl_down(u, 32); u += __shfl_down(u, 16);
    if (lane < 16) {
      nqp[(size_t)(chunk * 12 + bh) * 32 + fr * 16 + lane] = v;
      nkp[(size_t)(chunk * 12 + bh) * 32 + fr * 16 + lane] = u;
    }
  }
}

// ---------------- reduce partials ----------------
__global__ __launch_bounds__(256) void reduce_gram(
    const float* __restrict__ Gp, const float* __restrict__ nqp, const float* __restrict__ nkp,
    float* __restrict__ G, float* __restrict__ nq, float* __restrict__ nk) {
  const int i = blockIdx.x * 256 + threadIdx.x;
  if (i < 12 * 1024) {
    float s = 0.f;
    for (int ch = 0; ch < NCHUNKS; ++ch) s += Gp[(size_t)ch * 12288 + i];
    G[i] = s;
  } else if (i < 12 * 1024 + 384) {
    const int j = i - 12 * 1024;
    float s = 0.f;
    for (int ch = 0; ch < NCHUNKS; ++ch) s += nqp[(size_t)ch * 384 + j];
    nq[j] = s;
  } else if (i < 12 * 1024 + 768) {
    const int j = i - 12 * 1024 - 384;
    float s = 0.f;
    for (int ch = 0; ch < NCHUNKS; ++ch) s += nkp[(size_t)ch * 384 + j];
    nk[j] = s;
  }
}

// ---------------- softmax + fold proj: M[b] = proj_w @ blockdiag(attn) ----------------
__global__ __launch_bounds__(256) void attn_proj(
    const float* __restrict__ G, const float* __restrict__ nq, const float* __restrict__ nk,
    const float* __restrict__ temp, const float* __restrict__ proj_w,
    unsigned short* __restrict__ Mout) {
  const int h = blockIdx.x, b = blockIdx.y;
  const int bh = b * 6 + h;
  const int t = threadIdx.x;
  __shared__ float sc[32][33];
  __shared__ float nrmq[32], nrmk[32];
  if (t < 32) nrmq[t] = fmaxf(sqrtf(nq[bh * 32 + t]), 1e-12f);
  else if (t < 64) nrmk[t - 32] = fmaxf(sqrtf(nk[bh * 32 + t - 32]), 1e-12f);
  __syncthreads();
  const float tpr = temp[h];
  for (int i = t; i < 1024; i += 256) {
    const int c = i >> 5, d = i & 31;
    sc[c][d] = G[bh * 1024 + i] * tpr / (nrmq[c] * nrmk[d]);
  }
  __syncthreads();
  if (t < 32) {
    float mx = -1e30f;
    for (int d = 0; d < 32; ++d) mx = fmaxf(mx, sc[t][d]);
    float sum = 0.f;
    for (int d = 0; d < 32; ++d) { float e = __expf(sc[t][d] - mx); sc[t][d] = e; sum += e; }
    const float inv = 1.f / sum;
    for (int d = 0; d < 32; ++d) sc[t][d] *= inv;
  }
  __syncthreads();
  for (int i = t; i < 6144; i += 256) {
    const int co = i >> 5, d = i & 31;
    float acc = 0.f;
    for (int c = 0; c < 32; ++c) acc += proj_w[co * CC + h * 32 + c] * sc[c][d];
    Mout[((size_t)b * CC + co) * CC + h * 32 + d] = f2bf(acc);
  }
}

extern "C" void kernel_launch(void* const* d_in, const int* in_sizes, int n_in,
                              void* d_out, int out_size, void* d_ws, size_t ws_size,
                              hipStream_t stream) {
  const float* fg = (const float*)d_in[0];
  const float* fo = (const float*)d_in[1];
  const float* q_w = (const float*)d_in[2];
  const float* q_b = (const float*)d_in[3];
  const float* kv_w = (const float*)d_in[4];
  const float* kv_b = (const float*)d_in[5];
  const float* q_dw_w = (const float*)d_in[6];
  const float* q_dw_b = (const float*)d_in[7];
  const float* kv_dw_w = (const float*)d_in[8];
  const float* kv_dw_b = (const float*)d_in[9];
  const float* proj_w = (const float*)d_in[10];
  const float* proj_b = (const float*)d_in[11];
  const float* temp = (const float*)d_in[12];

  char* ws = (char*)d_ws;
  // bf16 plane (192ch, 2 batches) = 50331648 bytes
  unsigned short* QC  = (unsigned short*)(ws + 0);            // [b][192][n]
  unsigned short* KVC = (unsigned short*)(ws + 50331648);     // [b][384][n] (100663296 B)
  unsigned short* Qb  = (unsigned short*)(ws + 150994944);    // dw(QC)
  unsigned short* Kb  = (unsigned short*)(ws + 0);            // over dead QC
  unsigned short* Vb  = (unsigned short*)(ws + 50331648);     // over dead KVC K-half
  float* Gp  = (float*)(ws + 201326592);                      // [128][12][1024]
  float* nqp = (float*)(ws + 207618048);                      // [128][12][32]
  float* nkp = (float*)(ws + 207814656);
  float* G   = (float*)(ws + 208011264);                      // [12][1024]
  float* nqv = (float*)(ws + 208060416);
  float* nkv = (float*)(ws + 208061952);
  unsigned short* Mw  = (unsigned short*)(ws + 208063488);    // [2][192][192]
  unsigned short* Wq  = (unsigned short*)(ws + 208210944);    // [192][192]
  unsigned short* Wkv = (unsigned short*)(ws + 208284672);    // [384][192]

  cvt_w<<<dim3(54), dim3(256), 0, stream>>>(q_w, kv_w, Wq, Wkv);
  conv_gemm<1, 0, 0><<<dim3(512, 1, 2), dim3(512), 0, stream>>>(
      (const void*)fg, Wq, q_b, (void*)QC, 192, 1);
  conv_gemm<1, 0, 0><<<dim3(1024, 1, 2), dim3(512), 0, stream>>>(
      (const void*)fo, Wkv, kv_b, (void*)KVC, 384, 2);
  dwconv3x3<<<dim3(32, 192, 2), dim3(256), 0, stream>>>(QC, q_dw_w, q_dw_b, Qb, 192, 0);
  dwconv3x3<<<dim3(32, 192, 2), dim3(256), 0, stream>>>(KVC, kv_dw_w, kv_dw_b, Kb, 384, 0);
  dwconv3x3<<<dim3(32, 192, 2), dim3(256), 0, stream>>>(KVC, kv_dw_w, kv_dw_b, Vb, 384, 192);
  gram_kernel<<<dim3(NCHUNKS, 6, 2), dim3(64), 0, stream>>>(Qb, Kb, Gp, nqp, nkp);
  reduce_gram<<<dim3(51), dim3(256), 0, stream>>>(Gp, nqp, nkp, G, nqv, nkv);
  attn_proj<<<dim3(6, 2), dim3(256), 0, stream>>>(G, nqv, nkv, temp, proj_w, Mw);
  conv_gemm<0, 1, 1><<<dim3(512, 1, 2), dim3(512), 0, stream>>>(
      (const void*)Vb, Mw, proj_b, d_out, 192, 1);
}

// Round 4
// 300.376 us; speedup vs baseline: 1.4281x; 1.0363x over previous
//
#include <hip/hip_runtime.h>

#define HW_N 65536
#define CC 192
#define NCHUNKS 128

typedef __attribute__((ext_vector_type(8))) short short8v;
typedef __attribute__((ext_vector_type(4))) short short4v;
typedef __attribute__((ext_vector_type(4))) float f32x4;

__device__ __forceinline__ float bf2f(unsigned short u) {
  union { unsigned int i; float f; } v; v.i = ((unsigned int)u) << 16; return v.f;
}
__device__ __forceinline__ unsigned short f2bf(float f) {
  union { float f; unsigned int i; } v; v.f = f;
  unsigned int r = v.i + 0x7fffu + ((v.i >> 16) & 1u);
  return (unsigned short)(r >> 16);
}

// ---------------- weight preconversion f32 -> bf16 ----------------
__global__ __launch_bounds__(256) void cvt_w(
    const float* __restrict__ qw, const float* __restrict__ kvw,
    unsigned short* __restrict__ Wq, unsigned short* __restrict__ Wkv) {
  const int i = (blockIdx.x * 256 + threadIdx.x) * 8;
  const float* src; unsigned short* dst; int off;
  if (i < 36864) { src = qw; dst = Wq; off = i; }
  else { src = kvw; dst = Wkv; off = i - 36864; }
  unsigned short tmp[8];
#pragma unroll
  for (int j = 0; j < 8; ++j) tmp[j] = f2bf(src[off + j]);
  *(short8v*)(dst + off) = *(short8v*)tmp;
}

// ---------------- conv1x1 GEMM from NCHW input ----------------
// out[b][m][n] = sum_k W[m][k] * X[b][k][n] + bias[m]
// 512 thr = 8 waves; tile 192m x 128n; wave = 48m x 64n.
// Staging: thread = (n-quad nq=t&31, k-pair kp=t>>5): 2x f32x4 (or short4v) loads
// along n, pack (k,k+1) into u32, 4x ds_write_b32 into Bt[n][k].
// Epilogue: LDS repack Rp[96][144] -> coalesced 16B stores.
template <int INF32, int OUTF32, int PERB>
__global__ __launch_bounds__(512) void conv_gemm(
    const void* __restrict__ X_, const unsigned short* __restrict__ W,
    const float* __restrict__ bias, void* __restrict__ out_,
    int Mtot, int msplit) {
  __shared__ unsigned short Bt[2][128][40];
  __shared__ unsigned short Rp[96][144];
  const int d = blockIdx.x;
  int mt, nt;
  if (msplit == 2) { mt = (d >> 3) & 1; nt = (d & 7) | ((d >> 4) << 3); }
  else { mt = 0; nt = d; }
  const int m0 = mt * 192, n0 = nt * 128;
  const int b = blockIdx.z;
  const int t = threadIdx.x;
  const int lane = t & 63, wv = t >> 6;
  const int l15 = lane & 15, lg = lane >> 4;
  const int wm = wv & 3, wn = wv >> 2;
  const int mrow = m0 + wm * 48;
  const int nw = wn * 64;
  const int nq = t & 31;   // n = nq*4
  const int kp = t >> 5;   // k = kp*2 within chunk
  const size_t xb = (size_t)b * CC * (size_t)HW_N + n0 + nq * 4;
  const unsigned short* Wb = W + (PERB ? (size_t)b * Mtot * CC : 0);

  unsigned int pk[4];
  auto gload = [&](int kc) {
    const size_t xo = xb + (size_t)(kc * 32 + kp * 2) * (size_t)HW_N;
    if (INF32) {
      f32x4 v0 = *(const f32x4*)((const float*)X_ + xo);
      f32x4 v1 = *(const f32x4*)((const float*)X_ + xo + HW_N);
#pragma unroll
      for (int j = 0; j < 4; ++j)
        pk[j] = (unsigned int)f2bf(v0[j]) | ((unsigned int)f2bf(v1[j]) << 16);
    } else {
      short4v a0 = *(const short4v*)((const unsigned short*)X_ + xo);
      short4v a1 = *(const short4v*)((const unsigned short*)X_ + xo + HW_N);
#pragma unroll
      for (int j = 0; j < 4; ++j)
        pk[j] = (unsigned int)(unsigned short)a0[j] | ((unsigned int)(unsigned short)a1[j] << 16);
    }
  };
  auto lwrite = [&](int buf) {
#pragma unroll
    for (int j = 0; j < 4; ++j)
      *(unsigned int*)&Bt[buf][nq * 4 + j][kp * 2] = pk[j];
  };

  gload(0);
  lwrite(0);
  __syncthreads();

  f32x4 acc[3][4] = {};
  for (int kc = 0; kc < 6; ++kc) {
    const int buf = kc & 1;
    if (kc < 5) gload(kc + 1);  // T14: issue next loads before MFMA phase
    short8v af[3], bfr[4];
    const int k0 = kc * 32 + lg * 8;
#pragma unroll
    for (int fr = 0; fr < 3; ++fr)
      af[fr] = *(const short8v*)(Wb + (size_t)(mrow + fr * 16 + l15) * CC + k0);
#pragma unroll
    for (int fc = 0; fc < 4; ++fc)
      bfr[fc] = *(const short8v*)&Bt[buf][nw + fc * 16 + l15][lg * 8];
#pragma unroll
    for (int fr = 0; fr < 3; ++fr)
#pragma unroll
      for (int fc = 0; fc < 4; ++fc)
        acc[fr][fc] = __builtin_amdgcn_mfma_f32_16x16x32_bf16(af[fr], bfr[fc], acc[fr][fc], 0, 0, 0);
    if (kc < 5) lwrite(buf ^ 1);
    __syncthreads();
  }

  const size_t obase = (size_t)b * Mtot * (size_t)HW_N;
#pragma unroll
  for (int half = 0; half < 2; ++half) {
    if ((wm >> 1) == half) {
      const int mbase = (wm & 1) * 48;
#pragma unroll
      for (int fr = 0; fr < 3; ++fr) {
#pragma unroll
        for (int r = 0; r < 4; ++r) {
          const int mloc = mbase + fr * 16 + lg * 4 + r;
          const float bb = bias[m0 + half * 96 + mloc];
#pragma unroll
          for (int fc = 0; fc < 4; ++fc)
            Rp[mloc][nw + fc * 16 + l15] = f2bf(acc[fr][fc][r] + bb);
        }
      }
    }
    __syncthreads();
#pragma unroll
    for (int s = 0; s < 3; ++s) {
      const int idx = s * 512 + t;
      const int m = idx >> 4, n8 = (idx & 15) * 8;
      short8v v = *(short8v*)&Rp[m][n8];
      const size_t oo = obase + (size_t)(m0 + half * 96 + m) * HW_N + n0 + n8;
      if (OUTF32) {
        float tmp[8];
#pragma unroll
        for (int j = 0; j < 8; ++j) tmp[j] = bf2f((unsigned short)v[j]);
        *(f32x4*)((float*)out_ + oo) = *(f32x4*)&tmp[0];
        *(f32x4*)((float*)out_ + oo + 4) = *(f32x4*)&tmp[4];
      } else {
        *(short8v*)((unsigned short*)out_ + oo) = v;
      }
    }
    __syncthreads();
  }
}

// ---------------- depthwise 3x3, pad=1; all three tensors in one launch -------
__global__ __launch_bounds__(256) void dwconv3x3_all(
    const unsigned short* __restrict__ QC, const unsigned short* __restrict__ KVC,
    const float* __restrict__ q_dw_w, const float* __restrict__ q_dw_b,
    const float* __restrict__ kv_dw_w, const float* __restrict__ kv_dw_b,
    unsigned short* __restrict__ Qb, unsigned short* __restrict__ Kb,
    unsigned short* __restrict__ Vb) {
  const int t = threadIdx.x;
  const int wc = (t & 31) * 8;
  const int h = blockIdx.x * 8 + (t >> 5);
  const int y = blockIdx.y, b = blockIdx.z;
  const unsigned short* in; const float* w; float bv; unsigned short* out;
  if (y < 192) {
    in = QC + ((size_t)b * 192 + y) * (size_t)HW_N;
    w = q_dw_w + y * 9; bv = q_dw_b[y];
    out = Qb + ((size_t)b * 192 + y) * (size_t)HW_N;
  } else if (y < 384) {
    const int c = y - 192;
    in = KVC + ((size_t)b * 384 + c) * (size_t)HW_N;
    w = kv_dw_w + c * 9; bv = kv_dw_b[c];
    out = Kb + ((size_t)b * 192 + c) * (size_t)HW_N;
  } else {
    const int c = y - 384;
    in = KVC + ((size_t)b * 384 + 192 + c) * (size_t)HW_N;
    w = kv_dw_w + (192 + c) * 9; bv = kv_dw_b[192 + c];
    out = Vb + ((size_t)b * 192 + c) * (size_t)HW_N;
  }
  float wv9[9];
#pragma unroll
  for (int i = 0; i < 9; ++i) wv9[i] = w[i];
  float f[3][10];
#pragma unroll
  for (int ky = 0; ky < 3; ++ky) {
    const int hh = h + ky - 1;
    if (hh < 0 || hh > 255) {
#pragma unroll
      for (int j = 0; j < 10; ++j) f[ky][j] = 0.f;
    } else {
      const unsigned short* row = in + hh * 256;
      short8v v = *(const short8v*)(row + wc);
      f[ky][0] = (wc > 0) ? bf2f(row[wc - 1]) : 0.f;
#pragma unroll
      for (int j = 0; j < 8; ++j) f[ky][1 + j] = bf2f((unsigned short)v[j]);
      f[ky][9] = (wc < 248) ? bf2f(row[wc + 8]) : 0.f;
    }
  }
  union { short8v v; unsigned short u[8]; } o;
#pragma unroll
  for (int j = 0; j < 8; ++j) {
    float acc = bv;
#pragma unroll
    for (int ky = 0; ky < 3; ++ky)
#pragma unroll
      for (int kx = 0; kx < 3; ++kx)
        acc += wv9[ky * 3 + kx] * f[ky][j + kx];
    o.u[j] = f2bf(acc);
  }
  *(short8v*)(out + h * 256 + wc) = o.v;
}

// ---------------- Gram partials: G[c][d] = sum_n Q[c,n]K[d,n]; + sumsq ----------------
__global__ __launch_bounds__(64) void gram_kernel(
    const unsigned short* __restrict__ Q, const unsigned short* __restrict__ K,
    float* __restrict__ Gp, float* __restrict__ nqp, float* __restrict__ nkp) {
  const int lane = threadIdx.x;
  const int l15 = lane & 15, lg = lane >> 4;
  const int chunk = blockIdx.x, h = blockIdx.y, b = blockIdx.z;
  const int bh = b * 6 + h;
  const size_t base = ((size_t)b * CC + h * 32) * (size_t)HW_N;
  f32x4 acc[2][2] = {};
  float sq[2] = {0.f, 0.f}, sk[2] = {0.f, 0.f};
  const int nst = chunk * 512 + lg * 8;
  for (int ks = 0; ks < 16; ++ks) {
    const int n = nst + ks * 32;
    short8v qa[2], kb[2];
#pragma unroll
    for (int fr = 0; fr < 2; ++fr) {
      qa[fr] = *(const short8v*)(Q + base + (size_t)(fr * 16 + l15) * HW_N + n);
      kb[fr] = *(const short8v*)(K + base + (size_t)(fr * 16 + l15) * HW_N + n);
    }
#pragma unroll
    for (int fr = 0; fr < 2; ++fr)
#pragma unroll
      for (int j = 0; j < 8; ++j) {
        float a = bf2f((unsigned short)qa[fr][j]); sq[fr] += a * a;
        float c2 = bf2f((unsigned short)kb[fr][j]); sk[fr] += c2 * c2;
      }
#pragma unroll
    for (int fr = 0; fr < 2; ++fr)
#pragma unroll
      for (int fc = 0; fc < 2; ++fc)
        acc[fr][fc] = __builtin_amdgcn_mfma_f32_16x16x32_bf16(qa[fr], kb[fc], acc[fr][fc], 0, 0, 0);
  }
  float* Gb = Gp + (size_t)(chunk * 12 + bh) * 1024;
#pragma unroll
  for (int fr = 0; fr < 2; ++fr)
#pragma unroll
    for (int fc = 0; fc < 2; ++fc)
#pragma unroll
      for (int r = 0; r < 4; ++r)
        Gb[(fr * 16 + lg * 4 + r) * 32 + fc * 16 + l15] = acc[fr][fc][r];
#pragma unroll
  for (int fr = 0; fr < 2; ++fr) {
    float v = sq[fr]; v += __shfl_down(v, 32); v += __shfl_down(v, 16);
    float u = sk[fr]; u += __shfl_down(u, 32); u += __shfl_down(u, 16);
    if (lane < 16) {
      nqp[(size_t)(chunk * 12 + bh) * 32 + fr * 16 + lane] = v;
      nkp[(size_t)(chunk * 12 + bh) * 32 + fr * 16 + lane] = u;
    }
  }
}

// ---------------- reduce partials ----------------
__global__ __launch_bounds__(256) void reduce_gram(
    const float* __restrict__ Gp, const float* __restrict__ nqp, const float* __restrict__ nkp,
    float* __restrict__ G, float* __restrict__ nq, float* __restrict__ nk) {
  const int i = blockIdx.x * 256 + threadIdx.x;
  if (i < 12 * 1024) {
    float s = 0.f;
    for (int ch = 0; ch < NCHUNKS; ++ch) s += Gp[(size_t)ch * 12288 + i];
    G[i] = s;
  } else if (i < 12 * 1024 + 384) {
    const int j = i - 12 * 1024;
    float s = 0.f;
    for (int ch = 0; ch < NCHUNKS; ++ch) s += nqp[(size_t)ch * 384 + j];
    nq[j] = s;
  } else if (i < 12 * 1024 + 768) {
    const int j = i - 12 * 1024 - 384;
    float s = 0.f;
    for (int ch = 0; ch < NCHUNKS; ++ch) s += nkp[(size_t)ch * 384 + j];
    nk[j] = s;
  }
}

// ---------------- softmax + fold proj: M[b] = proj_w @ blockdiag(attn) ----------------
__global__ __launch_bounds__(256) void attn_proj(
    const float* __restrict__ G, const float* __restrict__ nq, const float* __restrict__ nk,
    const float* __restrict__ temp, const float* __restrict__ proj_w,
    unsigned short* __restrict__ Mout) {
  const int h = blockIdx.x, b = blockIdx.y;
  const int bh = b * 6 + h;
  const int t = threadIdx.x;
  __shared__ float sc[32][33];
  __shared__ float nrmq[32], nrmk[32];
  if (t < 32) nrmq[t] = fmaxf(sqrtf(nq[bh * 32 + t]), 1e-12f);
  else if (t < 64) nrmk[t - 32] = fmaxf(sqrtf(nk[bh * 32 + t - 32]), 1e-12f);
  __syncthreads();
  const float tpr = temp[h];
  for (int i = t; i < 1024; i += 256) {
    const int c = i >> 5, d = i & 31;
    sc[c][d] = G[bh * 1024 + i] * tpr / (nrmq[c] * nrmk[d]);
  }
  __syncthreads();
  if (t < 32) {
    float mx = -1e30f;
    for (int d = 0; d < 32; ++d) mx = fmaxf(mx, sc[t][d]);
    float sum = 0.f;
    for (int d = 0; d < 32; ++d) { float e = __expf(sc[t][d] - mx); sc[t][d] = e; sum += e; }
    const float inv = 1.f / sum;
    for (int d = 0; d < 32; ++d) sc[t][d] *= inv;
  }
  __syncthreads();
  for (int i = t; i < 6144; i += 256) {
    const int co = i >> 5, d = i & 31;
    float acc = 0.f;
    for (int c = 0; c < 32; ++c) acc += proj_w[co * CC + h * 32 + c] * sc[c][d];
    Mout[((size_t)b * CC + co) * CC + h * 32 + d] = f2bf(acc);
  }
}

extern "C" void kernel_launch(void* const* d_in, const int* in_sizes, int n_in,
                              void* d_out, int out_size, void* d_ws, size_t ws_size,
                              hipStream_t stream) {
  const float* fg = (const float*)d_in[0];
  const float* fo = (const float*)d_in[1];
  const float* q_w = (const float*)d_in[2];
  const float* q_b = (const float*)d_in[3];
  const float* kv_w = (const float*)d_in[4];
  const float* kv_b = (const float*)d_in[5];
  const float* q_dw_w = (const float*)d_in[6];
  const float* q_dw_b = (const float*)d_in[7];
  const float* kv_dw_w = (const float*)d_in[8];
  const float* kv_dw_b = (const float*)d_in[9];
  const float* proj_w = (const float*)d_in[10];
  const float* proj_b = (const float*)d_in[11];
  const float* temp = (const float*)d_in[12];

  char* ws = (char*)d_ws;
  unsigned short* QC  = (unsigned short*)(ws + 0);            // [b][192][n]
  unsigned short* KVC = (unsigned short*)(ws + 50331648);     // [b][384][n]
  unsigned short* Qb  = (unsigned short*)(ws + 150994944);    // dw(QC)
  unsigned short* Kb  = (unsigned short*)(ws + 0);            // over dead QC
  unsigned short* Vb  = (unsigned short*)(ws + 50331648);     // over dead KVC K-half
  float* Gp  = (float*)(ws + 201326592);                      // [128][12][1024]
  float* nqp = (float*)(ws + 207618048);                      // [128][12][32]
  float* nkp = (float*)(ws + 207814656);
  float* G   = (float*)(ws + 208011264);                      // [12][1024]
  float* nqv = (float*)(ws + 208060416);
  float* nkv = (float*)(ws + 208061952);
  unsigned short* Mw  = (unsigned short*)(ws + 208063488);    // [2][192][192]
  unsigned short* Wq  = (unsigned short*)(ws + 208210944);    // [192][192]
  unsigned short* Wkv = (unsigned short*)(ws + 208284672);    // [384][192]

  cvt_w<<<dim3(54), dim3(256), 0, stream>>>(q_w, kv_w, Wq, Wkv);
  conv_gemm<1, 0, 0><<<dim3(512, 1, 2), dim3(512), 0, stream>>>(
      (const void*)fg, Wq, q_b, (void*)QC, 192, 1);
  conv_gemm<1, 0, 0><<<dim3(1024, 1, 2), dim3(512), 0, stream>>>(
      (const void*)fo, Wkv, kv_b, (void*)KVC, 384, 2);
  dwconv3x3_all<<<dim3(32, 576, 2), dim3(256), 0, stream>>>(
      QC, KVC, q_dw_w, q_dw_b, kv_dw_w, kv_dw_b, Qb, Kb, Vb);
  gram_kernel<<<dim3(NCHUNKS, 6, 2), dim3(64), 0, stream>>>(Qb, Kb, Gp, nqp, nkp);
  reduce_gram<<<dim3(51), dim3(256), 0, stream>>>(Gp, nqp, nkp, G, nqv, nkv);
  attn_proj<<<dim3(6, 2), dim3(256), 0, stream>>>(G, nqv, nkv, temp, proj_w, Mw);
  conv_gemm<0, 1, 1><<<dim3(512, 1, 2), dim3(512), 0, stream>>>(
      (const void*)Vb, Mw, proj_b, d_out, 192, 1);
}